// Round 5
// baseline (19909.036 us; speedup 1.0000x reference)
//
#include <hip/hip_runtime.h>
#include <math.h>

#define DEV __device__ __forceinline__
typedef __attribute__((ext_vector_type(4))) float f32x4;

constexpr int BATCH = 64;
constexpr int TSTEP = 128;
constexpr int IDIM  = 128;
constexpr int HDIM  = 512;
constexpr int VDIM  = 32;
constexpr int LDEC  = 64;
constexpr int NBLK  = 256;
constexpr int BDIM  = 256;
constexpr unsigned MAGIC = 0x1357BD1u;
constexpr unsigned SPIN_LIMIT = 1u << 22;   // ~150ms; only on deadlock

// workspace layout (bytes)
constexpr size_t OFF_BAR  = 0;                                        // 4 KiB of barrier lines
constexpr size_t OFF_SIGT = 4096;                                     // signal^T [T][I][B] 4 MiB (plain, immutable)
constexpr size_t OFF_HT   = OFF_SIGT + (size_t)TSTEP*IDIM*BATCH*4;    // h^T [par][dir][H][B] (sc1)
constexpr size_t OFF_XD   = OFF_HT   + (size_t)2*2*HDIM*BATCH*4;      // xdec^T [V][B] (sc1)
constexpr size_t OFF_PAD  = OFF_XD   + (size_t)VDIM*BATCH*4;          // 8 KiB pad (uniform x-chunk overread)
constexpr size_t OFF_HT2  = OFF_PAD  + 8192;                          // h b-major [par][B][2H] (sc1)
constexpr size_t WS_NEED  = OFF_HT2  + (size_t)2*BATCH*2*HDIM*4;      // ~5.03 MiB

// bar line map (line = 32 u32 = 128B):
// 0 MAGIC | 1-8 joint grp | 9 joint root | 10 joint gen | 11 dead
// 12-15 dir0 grp | 16 dir0 root | 17 dir0 gen | 18-21 dir1 grp | 22 dir1 root | 23 dir1 gen
// 24-25 logit grp | 26 logit root | 28 xd_seq | 29 legacy cnt | 30 legacy gen

DEV unsigned ldu(const unsigned* p){ return __hip_atomic_load(p, __ATOMIC_RELAXED, __HIP_MEMORY_SCOPE_AGENT); }
DEV void     stu(unsigned* p, unsigned v){ __hip_atomic_store(p, v, __ATOMIC_RELAXED, __HIP_MEMORY_SCOPE_AGENT); }
DEV unsigned fau(unsigned* p, unsigned v){ return __hip_atomic_fetch_add(p, v, __ATOMIC_RELAXED, __HIP_MEMORY_SCOPE_AGENT); }
DEV void     ast(float* p, float v){ __hip_atomic_store(p, v, __ATOMIC_RELAXED, __HIP_MEMORY_SCOPE_AGENT); }
DEV void wait_vm0(){ asm volatile("s_waitcnt vmcnt(0)" ::: "memory"); }
DEV f32x4 gl4_sc1(const float* p){ f32x4 r; asm volatile("global_load_dwordx4 %0, %1, off sc1" : "=v"(r) : "v"(p)); return r; }
DEV f32x4 gl4_pln(const float* p){ f32x4 r; asm volatile("global_load_dwordx4 %0, %1, off"     : "=v"(r) : "v"(p)); return r; }
DEV void  gs4_sc1(float* p, f32x4 v){ asm volatile("global_store_dwordx4 %0, %1, off sc1" :: "v"(p), "v"(v) : "memory"); }
// block barrier that does NOT drain vmcnt (keeps prefetch in flight); orders LDS only
DEV void bar_lds(){
  asm volatile("s_waitcnt lgkmcnt(0)" ::: "memory");
  __builtin_amdgcn_s_barrier();
  asm volatile("" ::: "memory");
}

DEV void spin_ge(const unsigned* p, unsigned tgt, unsigned* dead) {
  unsigned spins = 0;
  while (ldu(p) < tgt) {
    __builtin_amdgcn_s_sleep(1);
    if ((++spins & 255u) == 0u) {
      if (ldu(dead)) break;
      if (spins > SPIN_LIMIT) { stu(dead, 1u); break; }
    }
  }
}

// hierarchical barrier: groups of grpsz on lines [gline..gline+ngrp), root at gline+ngrp, gen at genline
DEV void hbar(unsigned* bar, int gline, int grp, int ngrp, unsigned grpsz, int genline, unsigned* dead) {
  wait_vm0();
  __syncthreads();
  if (threadIdx.x == 0) {
    unsigned* gen = bar + genline*32;
    unsigned g = ldu(gen);
    unsigned* gc = bar + (gline + grp)*32;
    unsigned a = fau(gc, 1u);
    bool rel = false;
    if (a == grpsz - 1u) {
      stu(gc, 0u);
      unsigned* rt = bar + (gline + ngrp)*32;
      unsigned ra = fau(rt, 1u);
      if (ra == (unsigned)ngrp - 1u) { stu(rt, 0u); fau(gen, 1u); rel = true; }
    }
    if (!rel) spin_ge(gen, g + 1u, dead);
  }
  __syncthreads();
}

// prologue-only flat barrier WITH acq/rel fences (publishes plain sigT stores across XCDs)
DEV void gbar_full(unsigned* cnt, unsigned* gen, unsigned nb, unsigned* dead) {
  __syncthreads();
  if (threadIdx.x == 0) {
    unsigned g = ldu(gen);
    unsigned a = __hip_atomic_fetch_add(cnt, 1u, __ATOMIC_ACQ_REL, __HIP_MEMORY_SCOPE_AGENT);
    if (a >= nb - 1u) {
      stu(cnt, 0u);
      __hip_atomic_fetch_add(gen, 1u, __ATOMIC_RELEASE, __HIP_MEMORY_SCOPE_AGENT);
    } else {
      spin_ge(gen, g + 1u, dead);
      (void)__hip_atomic_load(gen, __ATOMIC_ACQUIRE, __HIP_MEMORY_SCOPE_AGENT);
    }
  }
  __syncthreads();
}

// LSTM cell gate-dots, depth-2 pipelined chunks of 64 k through LDS double-buffer.
// Encoder: chunks 0-1 = x (sigT, plain), 2-9 = h (sc1). Decoder: 0-7 = h, 8 = x (xdT, 32 valid k).
template<bool DEC>
DEV void cell(float acc[4], const float* __restrict__ xsrc, const float* __restrict__ hcur,
              const float* const* wx, const float* const* wh,
              int b, int tid, float* __restrict__ buf,
              const unsigned* xdflag, unsigned xdtgt, unsigned* dead)
{
  constexpr int NC = DEC ? 9 : 10;
  f32x4 a0,a1,a2,a3, b0,b1,b2,b3;
  auto addr = [&](int c)->const float* {
    if (DEC) return (c < 8) ? hcur + (size_t)c*4096 + tid*4 : xsrc + tid*4;
    return (c < 2) ? xsrc + (size_t)c*4096 + tid*4 : hcur + (size_t)(c-2)*4096 + tid*4;
  };
  auto issueA = [&](int c){ const float* s = addr(c);
    if (!DEC && c < 2) { a0=gl4_pln(s); a1=gl4_pln(s+1024); a2=gl4_pln(s+2048); a3=gl4_pln(s+3072); }
    else               { a0=gl4_sc1(s); a1=gl4_sc1(s+1024); a2=gl4_sc1(s+2048); a3=gl4_sc1(s+3072); } };
  auto issueB = [&](int c){ const float* s = addr(c);
    if (!DEC && c < 2) { b0=gl4_pln(s); b1=gl4_pln(s+1024); b2=gl4_pln(s+2048); b3=gl4_pln(s+3072); }
    else               { b0=gl4_sc1(s); b1=gl4_sc1(s+1024); b2=gl4_sc1(s+2048); b3=gl4_sc1(s+3072); } };

  issueA(0); issueB(1);
  #pragma unroll
  for (int c = 0; c < NC; ++c) {
    if (c + 1 < NC) asm volatile("s_waitcnt vmcnt(4)" ::: "memory");  // chunk c landed, c+1 in flight
    else            asm volatile("s_waitcnt vmcnt(0)" ::: "memory");
    float* dst = buf + (c & 1)*4096;
    if ((c & 1) == 0) {
      *(f32x4*)(dst + tid*4)        = a0; *(f32x4*)(dst + tid*4 + 1024) = a1;
      *(f32x4*)(dst + tid*4 + 2048) = a2; *(f32x4*)(dst + tid*4 + 3072) = a3;
    } else {
      *(f32x4*)(dst + tid*4)        = b0; *(f32x4*)(dst + tid*4 + 1024) = b1;
      *(f32x4*)(dst + tid*4 + 2048) = b2; *(f32x4*)(dst + tid*4 + 3072) = b3;
    }
    bar_lds();                                          // publish LDS; vmcnt NOT drained
    if (DEC && c == NC - 3) {                           // before issuing the x-chunk: fresh xdT
      if (tid == 0) spin_ge(xdflag, xdtgt, dead);
      bar_lds();
    }
    if (c + 2 < NC) { if ((c & 1) == 0) issueA(c + 2); else issueB(c + 2); }
    const float* bs = dst + b;
    if (DEC ? (c < 8) : (c >= 2)) {
      const int ch = DEC ? c : c - 2;
      const float *g0=wh[0]+ch*64, *g1=wh[1]+ch*64, *g2=wh[2]+ch*64, *g3=wh[3]+ch*64;
      #pragma unroll
      for (int kk = 0; kk < 64; ++kk) { float xv = bs[kk*64];
        acc[0]+=g0[kk]*xv; acc[1]+=g1[kk]*xv; acc[2]+=g2[kk]*xv; acc[3]+=g3[kk]*xv; }
    } else if (!DEC) {
      const float *g0=wx[0]+c*64, *g1=wx[1]+c*64, *g2=wx[2]+c*64, *g3=wx[3]+c*64;
      #pragma unroll
      for (int kk = 0; kk < 64; ++kk) { float xv = bs[kk*64];
        acc[0]+=g0[kk]*xv; acc[1]+=g1[kk]*xv; acc[2]+=g2[kk]*xv; acc[3]+=g3[kk]*xv; }
    } else {
      const float *g0=wx[0], *g1=wx[1], *g2=wx[2], *g3=wx[3];
      #pragma unroll
      for (int kk = 0; kk < 32; ++kk) { float xv = bs[kk*64];
        acc[0]+=g0[kk]*xv; acc[1]+=g1[kk]*xv; acc[2]+=g2[kk]*xv; acc[3]+=g3[kk]*xv; }
    }
  }
}

__global__ void __launch_bounds__(BDIM)
encdec(const float* __restrict__ signal, const float* __restrict__ tgt,
       const float* __restrict__ eWih, const float* __restrict__ eWhh,
       const float* __restrict__ eBih, const float* __restrict__ eBhh,
       const float* __restrict__ dWih, const float* __restrict__ dWhh,
       const float* __restrict__ dBih, const float* __restrict__ dBhh,
       const float* __restrict__ Wout, const float* __restrict__ bOut,
       float* __restrict__ out,
       unsigned* __restrict__ bar, float* __restrict__ sigT,
       float* __restrict__ hT, float* __restrict__ xdT, float* __restrict__ hT2)
{
  __shared__ __align__(16) float buf[2*4096];
  __shared__ __align__(16) float red[BDIM];
  const int blk = blockIdx.x, tid = threadIdx.x;
  const int d  = blk >> 7;
  const int js = blk & 127;
  const int b  = tid & 63;
  const int jj = tid >> 6;
  const int j  = js*4 + jj;

  unsigned* dead  = bar + 11*32;
  unsigned* xdseq = bar + 28*32;
  if (blk == 0 && tid == 0) {
    for (int q = 1; q <= 30; ++q) stu(bar + q*32, 0u);
    stu(xdseq, 1u);                                   // x_0 ready after prologue
    __hip_atomic_store(bar, MAGIC, __ATOMIC_RELEASE, __HIP_MEMORY_SCOPE_AGENT);
  }
  if (tid == 0) {
    unsigned spins = 0;
    while (__hip_atomic_load(bar, __ATOMIC_RELAXED, __HIP_MEMORY_SCOPE_AGENT) != MAGIC) {
      __builtin_amdgcn_s_sleep(1);
      if (++spins > SPIN_LIMIT) break;
    }
    (void)__hip_atomic_load(bar, __ATOMIC_ACQUIRE, __HIP_MEMORY_SCOPE_AGENT);
  }
  __syncthreads();

  // ---- prologue: transpose signal -> sigT[t][i][b] ----
  {
    const int t = blk & 127, ih = blk >> 7;
    float* tile = buf;                                 // [64][65] padded
    for (int idx = tid; idx < 64*64; idx += BDIM) {
      int il = idx & 63, bb = idx >> 6;
      tile[il*65 + bb] = signal[((size_t)bb*TSTEP + t)*IDIM + ih*64 + il];
    }
    __syncthreads();
    for (int idx = tid; idx < 64*64; idx += BDIM) {
      int bb = idx & 63, il = idx >> 6;
      sigT[((size_t)t*IDIM + ih*64 + il)*64 + bb] = tile[il*65 + bb];
    }
  }
  ast(&hT[((size_t)(0*2 + d)*HDIM + j)*64 + b], 0.f);
  ast(&hT[((size_t)(1*2 + d)*HDIM + j)*64 + b], 0.f);
  if (blk < BATCH && tid < VDIM) {
    float tv = tgt[((size_t)blk*LDEC)*VDIM + tid];
    ast(&xdT[tid*64 + blk], tv > 0.f ? tv : 0.f);
  }
  gbar_full(bar + 29*32, bar + 30*32, NBLK, dead);     // fenced: publish sigT

  // ---- encoder ----
  const float* wx[4]; const float* wh[4]; float bsum[4];
  #pragma unroll
  for (int g = 0; g < 4; ++g) {
    int r = __builtin_amdgcn_readfirstlane(g*HDIM + j);
    wx[g] = eWih + ((size_t)d*4*HDIM + r)*IDIM;
    wh[g] = eWhh + ((size_t)d*4*HDIM + r)*HDIM;
    bsum[g] = eBih[d*4*HDIM + r] + eBhh[d*4*HDIM + r];
  }
  float cst = 0.f;
  for (int t = 0; t < TSTEP; ++t) {
    const int cur = t & 1, nxt = cur ^ 1;
    const int td = d ? (TSTEP - 1 - t) : t;
    float acc[4] = {0.f, 0.f, 0.f, 0.f};
    cell<false>(acc, sigT + (size_t)td*IDIM*64, hT + ((size_t)(cur*2 + d)*HDIM)*64,
                wx, wh, b, tid, buf, nullptr, 0u, dead);
    float gi = acc[0]+bsum[0], gf = acc[1]+bsum[1], gg = acc[2]+bsum[2], go = acc[3]+bsum[3];
    float si = 1.f/(1.f+expf(-gi)), sf = 1.f/(1.f+expf(-gf)), so = 1.f/(1.f+expf(-go));
    cst = sf*cst + si*tanhf(gg);
    ast(&hT[((size_t)(nxt*2 + d)*HDIM + j)*64 + b], so*tanhf(cst));
    hbar(bar, d ? 18 : 12, (blk >> 5) & 3, 4, 32u, d ? 23 : 17, dead);   // per-dir
  }
  hbar(bar, 1, blk & 7, 8, 32u, 10, dead);             // joint

  // ---- decoder ----
  #pragma unroll
  for (int g = 0; g < 4; ++g) {
    int r = __builtin_amdgcn_readfirstlane(g*HDIM + j);
    wx[g] = dWih + ((size_t)d*4*HDIM + r)*VDIM;
    wh[g] = dWhh + ((size_t)d*4*HDIM + r)*HDIM;
    bsum[g] = dBih[d*4*HDIM + r] + dBhh[d*4*HDIM + r];
  }
  for (int s = 0; s < LDEC; ++s) {
    const int cur = s & 1, nxt = cur ^ 1;
    float acc[4] = {0.f, 0.f, 0.f, 0.f};
    cell<true>(acc, xdT, hT + ((size_t)(cur*2 + d)*HDIM)*64,
               wx, wh, b, tid, buf, xdseq, (unsigned)(s + 1), dead);
    float gi = acc[0]+bsum[0], gf = acc[1]+bsum[1], gg = acc[2]+bsum[2], go = acc[3]+bsum[3];
    float si = 1.f/(1.f+expf(-gi)), sf = 1.f/(1.f+expf(-gf)), so = 1.f/(1.f+expf(-go));
    cst = sf*cst + si*tanhf(gg);
    float hnew = so*tanhf(cst);
    ast(&hT[((size_t)(nxt*2 + d)*HDIM + j)*64 + b], hnew);
    red[b*4 + jj] = hnew;                              // LDS transpose for b-major mirror
    __syncthreads();
    if (tid < 64)
      gs4_sc1(hT2 + ((size_t)(nxt*BATCH + tid))*1024 + d*512 + js*4, *(f32x4*)&red[tid*4]);
    hbar(bar, 1, blk & 7, 8, 32u, 10, dead);           // h-ready (drains hT/hT2 stores)

    if (blk < BATCH) {                                 // logits/argmax/log_softmax
      const int bb = blk, v = tid & 31, kc = tid >> 5;
      f32x4 hv = gl4_sc1(hT2 + ((size_t)(nxt*BATCH + bb))*1024 + tid*4);
      wait_vm0();
      *(f32x4*)(buf + tid*4) = hv;
      __syncthreads();
      float part = 0.f;
      const float* wr = Wout + (size_t)v*(2*HDIM) + kc*128;
      const float* hb = buf + kc*128;
      #pragma unroll
      for (int i = 0; i < 128; i += 4) {
        f32x4 w = *(const f32x4*)(wr + i);
        f32x4 h4 = *(const f32x4*)(hb + i);
        part += w[0]*h4[0] + w[1]*h4[1] + w[2]*h4[2] + w[3]*h4[3];
      }
      red[tid] = part;
      __syncthreads();
      if (tid < VDIM) {
        float lg = red[tid];
        #pragma unroll
        for (int q = 1; q < 8; ++q) lg += red[tid + q*32];
        lg += bOut[tid];
        float m = lg; int mi = tid;                    // argmax, first-index tie rule
        #pragma unroll
        for (int off = 16; off >= 1; off >>= 1) {
          float om = __shfl_xor(m, off, 64);
          int omi  = __shfl_xor(mi, off, 64);
          if (om > m || (om == m && omi < mi)) { m = om; mi = omi; }
        }
        float ex = expf(lg - m), ssum = ex;
        #pragma unroll
        for (int off = 16; off >= 1; off >>= 1) ssum += __shfl_xor(ssum, off, 64);
        out[((size_t)bb*LDEC + s)*VDIM + tid] = lg - m - logf(ssum);
        ast(&xdT[tid*64 + bb], (tid == mi) ? 1.f : 0.f);
      }
      if (tid == 0) {                                  // arrival-only mini-bar -> bump xd_seq
        wait_vm0();
        unsigned* gc = bar + (24 + ((blk >> 5) & 1))*32;
        unsigned a = fau(gc, 1u);
        if (a == 31u) {
          stu(gc, 0u);
          unsigned ra = fau(bar + 26*32, 1u);
          if (ra == 1u) { stu(bar + 26*32, 0u); fau(xdseq, 1u); }
        }
      }
    }
  }
}

extern "C" void kernel_launch(void* const* d_in, const int* in_sizes, int n_in,
                              void* d_out, int out_size, void* d_ws, size_t ws_size,
                              hipStream_t stream) {
  if (ws_size < WS_NEED) return;  // insufficient scratch: fail validation loudly
  char* base = (char*)d_ws;
  hipLaunchKernelGGL(encdec, dim3(NBLK), dim3(BDIM), 0, stream,
    (const float*)d_in[0],  (const float*)d_in[1],
    (const float*)d_in[2],  (const float*)d_in[3],
    (const float*)d_in[4],  (const float*)d_in[5],
    (const float*)d_in[6],  (const float*)d_in[7],
    (const float*)d_in[8],  (const float*)d_in[9],
    (const float*)d_in[10], (const float*)d_in[11],
    (float*)d_out,
    (unsigned*)(base + OFF_BAR), (float*)(base + OFF_SIGT),
    (float*)(base + OFF_HT),     (float*)(base + OFF_XD),
    (float*)(base + OFF_HT2));
}

// Round 6
// 4670.266 us; speedup vs baseline: 4.2629x; 4.2629x over previous
//
#include <hip/hip_runtime.h>
#include <math.h>

#define DEV __device__ __forceinline__
typedef __attribute__((ext_vector_type(4))) float f32x4;

constexpr int BATCH = 64;
constexpr int TSTEP = 128;
constexpr int IDIM  = 128;
constexpr int HDIM  = 512;
constexpr int VDIM  = 32;
constexpr int LDEC  = 64;
constexpr int NBLK  = 256;
constexpr int BDIM  = 256;
constexpr unsigned MAGIC = 0x1357BD1u;
constexpr unsigned SPIN_LIMIT = 1u << 22;   // only on deadlock

// workspace layout (bytes)
constexpr size_t OFF_BAR  = 0;                                        // 4 KiB barrier lines
constexpr size_t OFF_SIGT = 4096;                                     // signal^T [T][I][B] 4 MiB (plain, immutable)
constexpr size_t OFF_HT   = OFF_SIGT + (size_t)TSTEP*IDIM*BATCH*4;    // h^T [par][dir][H][B] (sc1 only)
constexpr size_t OFF_XD   = OFF_HT   + (size_t)2*2*HDIM*BATCH*4;      // xdec^T [V][B] (sc1 only)
constexpr size_t WS_NEED  = OFF_XD   + (size_t)VDIM*BATCH*4;

// bar line map (line = 32 u32 = 128B):
// 0 MAGIC | 1-8 joint grp | 9 joint root | 10 joint gen | 11 dead
// 12-15 dir0 grp | 16 dir0 root | 17 dir0 gen | 18-21 dir1 grp | 22 dir1 root | 23 dir1 gen
// 29 legacy cnt | 30 legacy gen (prologue fenced barrier)

DEV unsigned ldu(const unsigned* p){ return __hip_atomic_load(p, __ATOMIC_RELAXED, __HIP_MEMORY_SCOPE_AGENT); }
DEV void     stu(unsigned* p, unsigned v){ __hip_atomic_store(p, v, __ATOMIC_RELAXED, __HIP_MEMORY_SCOPE_AGENT); }
DEV unsigned fau(unsigned* p, unsigned v){ return __hip_atomic_fetch_add(p, v, __ATOMIC_RELAXED, __HIP_MEMORY_SCOPE_AGENT); }
DEV void     ast(float* p, float v){ __hip_atomic_store(p, v, __ATOMIC_RELAXED, __HIP_MEMORY_SCOPE_AGENT); }
DEV void wait_vm0(){ asm volatile("s_waitcnt vmcnt(0)" ::: "memory"); }
DEV f32x4 gl4_sc1(const float* p){ f32x4 r; asm volatile("global_load_dwordx4 %0, %1, off sc1" : "=v"(r) : "v"(p)); return r; }
DEV f32x4 gl4_pln(const float* p){ f32x4 r; asm volatile("global_load_dwordx4 %0, %1, off"     : "=v"(r) : "v"(p)); return r; }
DEV float gl1_sc1(const float* p){ float r; asm volatile("global_load_dword %0, %1, off sc1"   : "=v"(r) : "v"(p)); return r; }

DEV void spin_ge(const unsigned* p, unsigned tgt, unsigned* dead) {
  unsigned spins = 0;
  while (ldu(p) < tgt) {
    __builtin_amdgcn_s_sleep(1);
    if ((++spins & 255u) == 0u) {
      if (ldu(dead)) break;
      if (spins > SPIN_LIMIT) { stu(dead, 1u); break; }
    }
  }
}

// hierarchical barrier, no cache fences (shared data moves via sc1/L3 only).
// groups of grpsz on lines [gline..gline+ngrp), root at gline+ngrp, gen at genline.
DEV void hbar(unsigned* bar, int gline, int grp, int ngrp, unsigned grpsz, int genline, unsigned* dead) {
  wait_vm0();                        // this wave's sc1 stores complete at coherent point
  __syncthreads();                   // all waves of block drained
  if (threadIdx.x == 0) {
    unsigned* gen = bar + genline*32;
    unsigned g = ldu(gen);
    unsigned* gc = bar + (gline + grp)*32;
    unsigned a = fau(gc, 1u);
    bool rel = false;
    if (a == grpsz - 1u) {
      stu(gc, 0u);
      unsigned* rt = bar + (gline + ngrp)*32;
      unsigned ra = fau(rt, 1u);
      if (ra == (unsigned)ngrp - 1u) { stu(rt, 0u); fau(gen, 1u); rel = true; }
    }
    if (!rel) spin_ge(gen, g + 1u, dead);
  }
  __syncthreads();
}

// prologue-only flat barrier WITH acq/rel fences (publishes plain sigT stores across XCDs)
DEV void gbar_full(unsigned* cnt, unsigned* gen, unsigned nb, unsigned* dead) {
  __syncthreads();
  if (threadIdx.x == 0) {
    unsigned g = ldu(gen);
    unsigned a = __hip_atomic_fetch_add(cnt, 1u, __ATOMIC_ACQ_REL, __HIP_MEMORY_SCOPE_AGENT);
    if (a >= nb - 1u) {
      stu(cnt, 0u);
      __hip_atomic_fetch_add(gen, 1u, __ATOMIC_RELEASE, __HIP_MEMORY_SCOPE_AGENT);
    } else {
      spin_ge(gen, g + 1u, dead);
      (void)__hip_atomic_load(gen, __ATOMIC_ACQUIRE, __HIP_MEMORY_SCOPE_AGENT);
    }
  }
  __syncthreads();
}

// One LSTM cell step (round-4 structure: 88 VGPR, depth-1 prefetch under compute).
// K = KX (x part) + 512 (h part), chunked 64-k through LDS double-buffer.
template<int KX, bool XSC1>
DEV void cell_step(float acc[4], const float* __restrict__ xsrc,
                   const float* __restrict__ hcur,
                   const float* const* wx, const float* const* wh,
                   int b, int tid, float* __restrict__ buf)
{
  constexpr int  NXC = KX / 64;             // full 64-k x chunks (2 enc, 0 dec)
  constexpr bool XR  = (KX % 64) != 0;      // 32-k x chunk (dec)
  constexpr int  NC  = NXC + (XR ? 1 : 0) + HDIM / 64;
  f32x4 r[4];

  auto issue = [&](int c) {
    if (c < NXC) {
      const float* s = xsrc + (size_t)c*4096 + tid*4;
      #pragma unroll
      for (int q = 0; q < 4; ++q) r[q] = XSC1 ? gl4_sc1(s + q*1024) : gl4_pln(s + q*1024);
    } else if (XR && c == NXC) {
      const float* s = xsrc + tid*4;
      #pragma unroll
      for (int q = 0; q < 2; ++q) r[q] = XSC1 ? gl4_sc1(s + q*1024) : gl4_pln(s + q*1024);
    } else {
      const int ch = c - NXC - (XR ? 1 : 0);
      const float* s = hcur + (size_t)ch*4096 + tid*4;
      #pragma unroll
      for (int q = 0; q < 4; ++q) r[q] = gl4_sc1(s + q*1024);
    }
  };

  issue(0);
  for (int c = 0; c < NC; ++c) {
    wait_vm0();                                    // chunk-c loads landed
    float* dst = buf + (c & 1)*4096;
    const bool small = (XR && c == NXC);
    *(f32x4*)(dst + tid*4)        = r[0];
    *(f32x4*)(dst + tid*4 + 1024) = r[1];
    if (!small) {
      *(f32x4*)(dst + tid*4 + 2048) = r[2];
      *(f32x4*)(dst + tid*4 + 3072) = r[3];
    }
    __syncthreads();                               // publish buf[c&1]
    if (c + 1 < NC) issue(c + 1);                  // prefetch flies under compute
    const float *g0, *g1, *g2, *g3;
    if (c < NXC)            { g0=wx[0]+c*64; g1=wx[1]+c*64; g2=wx[2]+c*64; g3=wx[3]+c*64; }
    else if (XR && c==NXC)  { g0=wx[0];      g1=wx[1];      g2=wx[2];      g3=wx[3]; }
    else { const int ch=c-NXC-(XR?1:0); g0=wh[0]+ch*64; g1=wh[1]+ch*64; g2=wh[2]+ch*64; g3=wh[3]+ch*64; }
    const float* bs = dst + b;
    if (!small) {
      #pragma unroll
      for (int kk = 0; kk < 64; ++kk) {
        float xv = bs[kk*64];
        acc[0] += g0[kk]*xv; acc[1] += g1[kk]*xv; acc[2] += g2[kk]*xv; acc[3] += g3[kk]*xv;
      }
    } else {
      #pragma unroll
      for (int kk = 0; kk < 32; ++kk) {
        float xv = bs[kk*64];
        acc[0] += g0[kk]*xv; acc[1] += g1[kk]*xv; acc[2] += g2[kk]*xv; acc[3] += g3[kk]*xv;
      }
    }
  }
}

__global__ void __launch_bounds__(BDIM)
encdec(const float* __restrict__ signal, const float* __restrict__ tgt,
       const float* __restrict__ eWih, const float* __restrict__ eWhh,
       const float* __restrict__ eBih, const float* __restrict__ eBhh,
       const float* __restrict__ dWih, const float* __restrict__ dWhh,
       const float* __restrict__ dBih, const float* __restrict__ dBhh,
       const float* __restrict__ Wout, const float* __restrict__ bOut,
       float* __restrict__ out,
       unsigned* __restrict__ bar, float* __restrict__ sigT,
       float* __restrict__ hT, float* __restrict__ xdT)
{
  __shared__ __align__(16) float buf[2*4096];      // 32 KiB chunk double-buffer
  __shared__ float red[BDIM];
  const int blk = blockIdx.x, tid = threadIdx.x;
  const int d  = blk >> 7;
  const int js = blk & 127;
  const int b  = tid & 63;
  const int jj = tid >> 6;
  const int j  = js * 4 + jj;

  unsigned* dead = bar + 11*32;
  if (blk == 0 && tid == 0) {
    for (int q = 1; q <= 30; ++q) stu(bar + q*32, 0u);
    __hip_atomic_store(bar, MAGIC, __ATOMIC_RELEASE, __HIP_MEMORY_SCOPE_AGENT);
  }
  if (tid == 0) {
    unsigned spins = 0;
    while (__hip_atomic_load(bar, __ATOMIC_RELAXED, __HIP_MEMORY_SCOPE_AGENT) != MAGIC) {
      __builtin_amdgcn_s_sleep(1);
      if (++spins > SPIN_LIMIT) break;
    }
    (void)__hip_atomic_load(bar, __ATOMIC_ACQUIRE, __HIP_MEMORY_SCOPE_AGENT);
  }
  __syncthreads();

  // ---- prologue: transpose signal -> sigT[t][i][b] (plain; published by gbar_full) ----
  {
    const int t = blk & 127, ih = blk >> 7;
    float* tile = buf;                               // [64][65] padded
    for (int idx = tid; idx < 64*64; idx += BDIM) {
      int il = idx & 63, bb = idx >> 6;
      tile[il*65 + bb] = signal[((size_t)bb*TSTEP + t)*IDIM + ih*64 + il];
    }
    __syncthreads();
    for (int idx = tid; idx < 64*64; idx += BDIM) {
      int bb = idx & 63, il = idx >> 6;
      sigT[((size_t)t*IDIM + ih*64 + il)*64 + bb] = tile[il*65 + bb];
    }
  }
  // hT / xdT live exclusively in L3 (sc1) — init with agent stores so no L2 copies exist
  ast(&hT[((size_t)(0*2 + d)*HDIM + j)*64 + b], 0.f);
  ast(&hT[((size_t)(1*2 + d)*HDIM + j)*64 + b], 0.f);
  if (blk < BATCH && tid < VDIM) {
    float tv = tgt[((size_t)blk*LDEC)*VDIM + tid];
    ast(&xdT[tid*64 + blk], tv > 0.f ? tv : 0.f);
  }
  gbar_full(bar + 29*32, bar + 30*32, NBLK, dead);   // the ONLY fenced barrier

  // ---- encoder ----
  const float* wx[4]; const float* wh[4]; float bsum[4];
  #pragma unroll
  for (int g = 0; g < 4; ++g) {
    int r = __builtin_amdgcn_readfirstlane(g*HDIM + j);
    wx[g] = eWih + ((size_t)d*4*HDIM + r)*IDIM;
    wh[g] = eWhh + ((size_t)d*4*HDIM + r)*HDIM;
    bsum[g] = eBih[d*4*HDIM + r] + eBhh[d*4*HDIM + r];
  }
  float c = 0.f;
  for (int t = 0; t < TSTEP; ++t) {
    const int cur = t & 1, nxt = cur ^ 1;
    const int td = d ? (TSTEP - 1 - t) : t;
    float acc[4] = {0.f, 0.f, 0.f, 0.f};
    cell_step<IDIM, false>(acc, sigT + (size_t)td*IDIM*64,
                           hT + ((size_t)(cur*2 + d)*HDIM)*64, wx, wh, b, tid, buf);
    float gi = acc[0]+bsum[0], gf = acc[1]+bsum[1], gg = acc[2]+bsum[2], go = acc[3]+bsum[3];
    float si = 1.f/(1.f+expf(-gi)), sf = 1.f/(1.f+expf(-gf)), so = 1.f/(1.f+expf(-go));
    c = sf*c + si*tanhf(gg);
    ast(&hT[((size_t)(nxt*2 + d)*HDIM + j)*64 + b], so*tanhf(c));
    hbar(bar, d ? 18 : 12, (blk >> 5) & 3, 4, 32u, d ? 23 : 17, dead);  // per-dir hierarchical
  }
  hbar(bar, 1, blk & 7, 8, 32u, 10, dead);           // joint hierarchical

  // ---- decoder ----
  #pragma unroll
  for (int g = 0; g < 4; ++g) {
    int r = __builtin_amdgcn_readfirstlane(g*HDIM + j);
    wx[g] = dWih + ((size_t)d*4*HDIM + r)*VDIM;
    wh[g] = dWhh + ((size_t)d*4*HDIM + r)*HDIM;
    bsum[g] = dBih[d*4*HDIM + r] + dBhh[d*4*HDIM + r];
  }
  for (int s = 0; s < LDEC; ++s) {
    const int cur = s & 1, nxt = cur ^ 1;
    float acc[4] = {0.f, 0.f, 0.f, 0.f};
    cell_step<VDIM, true>(acc, xdT, hT + ((size_t)(cur*2 + d)*HDIM)*64, wx, wh, b, tid, buf);
    float gi = acc[0]+bsum[0], gf = acc[1]+bsum[1], gg = acc[2]+bsum[2], go = acc[3]+bsum[3];
    float si = 1.f/(1.f+expf(-gi)), sf = 1.f/(1.f+expf(-gf)), so = 1.f/(1.f+expf(-go));
    c = sf*c + si*tanhf(gg);
    ast(&hT[((size_t)(nxt*2 + d)*HDIM + j)*64 + b], so*tanhf(c));
    hbar(bar, 1, blk & 7, 8, 32u, 10, dead);         // h visible

    if (blk < BATCH) {                               // logits/argmax/log_softmax
      const int bb = blk, v = tid & 31, kc = tid >> 5;
      const float* hx = hT + (size_t)nxt*2*HDIM*64 + bb;   // [d][k][b] d-major = concat(hf,hb)
      float part = 0.f;
      float rr[32];
      for (int w = 0; w < 4; ++w) {                  // windows of 32 in-flight sc1 loads
        #pragma unroll
        for (int i = 0; i < 32; ++i)
          rr[i] = gl1_sc1(hx + (size_t)(kc*128 + w*32 + i)*64);
        wait_vm0();
        #pragma unroll
        for (int i = 0; i < 32; ++i)
          part += Wout[(size_t)v*(2*HDIM) + kc*128 + w*32 + i] * rr[i];
      }
      red[tid] = part;
      __syncthreads();
      if (tid < VDIM) {
        float lg = red[tid];
        #pragma unroll
        for (int q = 1; q < 8; ++q) lg += red[tid + q*32];
        lg += bOut[tid];
        float m = lg; int mi = tid;                  // argmax, first-index tie rule
        #pragma unroll
        for (int off = 16; off >= 1; off >>= 1) {
          float om = __shfl_xor(m, off, 64);
          int omi  = __shfl_xor(mi, off, 64);
          if (om > m || (om == m && omi < mi)) { m = om; mi = omi; }
        }
        float ex = expf(lg - m), ssum = ex;
        #pragma unroll
        for (int off = 16; off >= 1; off >>= 1) ssum += __shfl_xor(ssum, off, 64);
        out[((size_t)bb*LDEC + s)*VDIM + tid] = lg - m - logf(ssum);
        ast(&xdT[tid*64 + bb], (tid == mi) ? 1.f : 0.f);
      }
    }
    hbar(bar, 1, blk & 7, 8, 32u, 10, dead);         // one-hot visible
  }
}

extern "C" void kernel_launch(void* const* d_in, const int* in_sizes, int n_in,
                              void* d_out, int out_size, void* d_ws, size_t ws_size,
                              hipStream_t stream) {
  if (ws_size < WS_NEED) return;
  char* base = (char*)d_ws;
  hipLaunchKernelGGL(encdec, dim3(NBLK), dim3(BDIM), 0, stream,
    (const float*)d_in[0],  (const float*)d_in[1],
    (const float*)d_in[2],  (const float*)d_in[3],
    (const float*)d_in[4],  (const float*)d_in[5],
    (const float*)d_in[6],  (const float*)d_in[7],
    (const float*)d_in[8],  (const float*)d_in[9],
    (const float*)d_in[10], (const float*)d_in[11],
    (float*)d_out,
    (unsigned*)(base + OFF_BAR), (float*)(base + OFF_SIGT),
    (float*)(base + OFF_HT),     (float*)(base + OFF_XD));
}

// Round 7
// 4156.853 us; speedup vs baseline: 4.7894x; 1.1235x over previous
//
#include <hip/hip_runtime.h>
#include <math.h>

#define DEV __device__ __forceinline__
typedef __attribute__((ext_vector_type(4))) float f32x4;

constexpr int BATCH = 64;
constexpr int TSTEP = 128;
constexpr int IDIM  = 128;
constexpr int HDIM  = 512;
constexpr int VDIM  = 32;
constexpr int LDEC  = 64;
constexpr int NBLK  = 256;
constexpr int BDIM  = 256;
constexpr unsigned MAGIC = 0x1357BD1u;
constexpr unsigned SPIN_LIMIT = 1u << 22;   // only on deadlock

constexpr int WS_E = 644;    // enc LDS weight row stride (640 + pad, 16B-aligned)
constexpr int WS_D = 548;    // dec LDS weight row stride (544 + pad, 16B-aligned)
// shared carve-up (floats): buf 4096 | Wlds 10304 | red 256
constexpr int SM_BUF = 0, SM_W = 4096, SM_RED = 4096 + 10304, SM_TOT = 14656;

// workspace layout (bytes)
constexpr size_t OFF_BAR  = 0;                                        // 4 KiB barrier lines
constexpr size_t OFF_SIGT = 4096;                                     // signal^T [T][I][B] (plain, immutable)
constexpr size_t OFF_HT   = OFF_SIGT + (size_t)TSTEP*IDIM*BATCH*4;    // h^T [par][dir][H][B] (sc1 only)
constexpr size_t OFF_XD   = OFF_HT   + (size_t)2*2*HDIM*BATCH*4;      // xdec^T [V][B] (sc1 only)
constexpr size_t WS_NEED  = OFF_XD   + (size_t)VDIM*BATCH*4;

// bar line map: 0 MAGIC | 1-8 joint grp | 9 joint root | 10 joint gen | 11 dead
// 12-15 d0 grp | 16 d0 root | 17 d0 gen | 18-21 d1 grp | 22 d1 root | 23 d1 gen | 29/30 legacy

DEV unsigned ldu(const unsigned* p){ return __hip_atomic_load(p, __ATOMIC_RELAXED, __HIP_MEMORY_SCOPE_AGENT); }
DEV void     stu(unsigned* p, unsigned v){ __hip_atomic_store(p, v, __ATOMIC_RELAXED, __HIP_MEMORY_SCOPE_AGENT); }
DEV unsigned fau(unsigned* p, unsigned v){ return __hip_atomic_fetch_add(p, v, __ATOMIC_RELAXED, __HIP_MEMORY_SCOPE_AGENT); }
DEV void     ast(float* p, float v){ __hip_atomic_store(p, v, __ATOMIC_RELAXED, __HIP_MEMORY_SCOPE_AGENT); }
DEV void wait_vm0(){ asm volatile("s_waitcnt vmcnt(0)" ::: "memory"); }
DEV f32x4 gl4_sc1(const float* p){ f32x4 r; asm volatile("global_load_dwordx4 %0, %1, off sc1" : "=v"(r) : "v"(p)); return r; }
DEV f32x4 gl4_pln(const float* p){ f32x4 r; asm volatile("global_load_dwordx4 %0, %1, off"     : "=v"(r) : "v"(p)); return r; }
DEV float gl1_sc1(const float* p){ float r; asm volatile("global_load_dword %0, %1, off sc1"   : "=v"(r) : "v"(p)); return r; }

DEV void spin_ge(const unsigned* p, unsigned tgt, unsigned* dead) {
  unsigned spins = 0;
  while (ldu(p) < tgt) {
    __builtin_amdgcn_s_sleep(1);
    if ((++spins & 255u) == 0u) {
      if (ldu(dead)) break;
      if (spins > SPIN_LIMIT) { stu(dead, 1u); break; }
    }
  }
}

// hierarchical barrier, no cache fences (shared data moves via sc1/L3 only)
DEV void hbar(unsigned* bar, int gline, int grp, int ngrp, unsigned grpsz, int genline, unsigned* dead) {
  wait_vm0();
  __syncthreads();
  if (threadIdx.x == 0) {
    unsigned* gen = bar + genline*32;
    unsigned g = ldu(gen);
    unsigned* gc = bar + (gline + grp)*32;
    unsigned a = fau(gc, 1u);
    bool rel = false;
    if (a == grpsz - 1u) {
      stu(gc, 0u);
      unsigned* rt = bar + (gline + ngrp)*32;
      unsigned ra = fau(rt, 1u);
      if (ra == (unsigned)ngrp - 1u) { stu(rt, 0u); fau(gen, 1u); rel = true; }
    }
    if (!rel) spin_ge(gen, g + 1u, dead);
  }
  __syncthreads();
}

// prologue-only flat barrier WITH acq/rel fences (publishes plain sigT stores across XCDs)
DEV void gbar_full(unsigned* cnt, unsigned* gen, unsigned nb, unsigned* dead) {
  __syncthreads();
  if (threadIdx.x == 0) {
    unsigned g = ldu(gen);
    unsigned a = __hip_atomic_fetch_add(cnt, 1u, __ATOMIC_ACQ_REL, __HIP_MEMORY_SCOPE_AGENT);
    if (a >= nb - 1u) {
      stu(cnt, 0u);
      __hip_atomic_fetch_add(gen, 1u, __ATOMIC_RELEASE, __HIP_MEMORY_SCOPE_AGENT);
    } else {
      spin_ge(gen, g + 1u, dead);
      (void)__hip_atomic_load(gen, __ATOMIC_ACQUIRE, __HIP_MEMORY_SCOPE_AGENT);
    }
  }
  __syncthreads();
}

// LSTM cell gate-dots. Weights LDS-resident (row = ju*4+g, stride WS, broadcast b128 reads).
// x/h panel streamed in 32-k chunks (2 KiB/thread-group) through LDS double-buffer,
// depth-1 register prefetch under compute. KX = 128 (enc) or 32 (dec).
template<int KX, int WS, bool XSC1>
DEV void cell_step(float acc[4], const float* __restrict__ xsrc,
                   const float* __restrict__ hcur, const float* __restrict__ Wl,
                   int b, int jj, int tid, float* __restrict__ buf)
{
  constexpr int NXC = KX / 32;
  constexpr int NC  = NXC + HDIM / 32;
  f32x4 r0, r1;
  auto issue = [&](int c) {
    const float* s = (c < NXC) ? xsrc + (size_t)c*2048 + tid*8
                               : hcur + (size_t)(c - NXC)*2048 + tid*8;
    if (c < NXC && !XSC1) { r0 = gl4_pln(s); r1 = gl4_pln(s + 4); }
    else                  { r0 = gl4_sc1(s); r1 = gl4_sc1(s + 4); }
  };
  issue(0);
  for (int c = 0; c < NC; ++c) {
    wait_vm0();                               // chunk-c loads landed
    float* dst = buf + (c & 1)*2048;
    *(f32x4*)(dst + tid*8)     = r0;
    *(f32x4*)(dst + tid*8 + 4) = r1;
    __syncthreads();                          // publish buf[c&1] (safe: see hazard audit)
    if (c + 1 < NC) issue(c + 1);             // prefetch flies under compute
    const float* wr = Wl + (size_t)(jj*4)*WS + c*32;
    const float* bs = dst + b;
    #pragma unroll
    for (int kq = 0; kq < 8; ++kq) {
      f32x4 w0 = *(const f32x4*)(wr + 0*WS + kq*4);   // broadcast (lane-uniform)
      f32x4 w1 = *(const f32x4*)(wr + 1*WS + kq*4);
      f32x4 w2 = *(const f32x4*)(wr + 2*WS + kq*4);
      f32x4 w3 = *(const f32x4*)(wr + 3*WS + kq*4);
      float x0 = bs[(kq*4+0)*64], x1 = bs[(kq*4+1)*64];
      float x2 = bs[(kq*4+2)*64], x3 = bs[(kq*4+3)*64];
      acc[0] += w0[0]*x0 + w0[1]*x1 + w0[2]*x2 + w0[3]*x3;
      acc[1] += w1[0]*x0 + w1[1]*x1 + w1[2]*x2 + w1[3]*x3;
      acc[2] += w2[0]*x0 + w2[1]*x1 + w2[2]*x2 + w2[3]*x3;
      acc[3] += w3[0]*x0 + w3[1]*x1 + w3[2]*x2 + w3[3]*x3;
    }
  }
}

__global__ void __launch_bounds__(BDIM)
encdec(const float* __restrict__ signal, const float* __restrict__ tgt,
       const float* __restrict__ eWih, const float* __restrict__ eWhh,
       const float* __restrict__ eBih, const float* __restrict__ eBhh,
       const float* __restrict__ dWih, const float* __restrict__ dWhh,
       const float* __restrict__ dBih, const float* __restrict__ dBhh,
       const float* __restrict__ Wout, const float* __restrict__ bOut,
       float* __restrict__ out,
       unsigned* __restrict__ bar, float* __restrict__ sigT,
       float* __restrict__ hT, float* __restrict__ xdT)
{
  __shared__ __align__(16) float smem[SM_TOT];     // 57.25 KiB: buf | Wlds | red
  float* buf = smem + SM_BUF;
  float* Wl  = smem + SM_W;
  float* red = smem + SM_RED;
  const int blk = blockIdx.x, tid = threadIdx.x;
  const int d  = blk >> 7;
  const int js = blk & 127;
  const int b  = tid & 63;
  const int jj = tid >> 6;
  const int j  = js * 4 + jj;

  unsigned* dead = bar + 11*32;
  if (blk == 0 && tid == 0) {
    for (int q = 1; q <= 30; ++q) stu(bar + q*32, 0u);
    __hip_atomic_store(bar, MAGIC, __ATOMIC_RELEASE, __HIP_MEMORY_SCOPE_AGENT);
  }
  if (tid == 0) {
    unsigned spins = 0;
    while (__hip_atomic_load(bar, __ATOMIC_RELAXED, __HIP_MEMORY_SCOPE_AGENT) != MAGIC) {
      __builtin_amdgcn_s_sleep(1);
      if (++spins > SPIN_LIMIT) break;
    }
    (void)__hip_atomic_load(bar, __ATOMIC_ACQUIRE, __HIP_MEMORY_SCOPE_AGENT);
  }
  __syncthreads();

  // ---- prologue: transpose signal -> sigT[t][i][b] (plain; published by gbar_full) ----
  {
    const int t = blk & 127, ih = blk >> 7;
    float* tile = smem;                              // [64][65] padded (4160 floats)
    for (int idx = tid; idx < 64*64; idx += BDIM) {
      int il = idx & 63, bb = idx >> 6;
      tile[il*65 + bb] = signal[((size_t)bb*TSTEP + t)*IDIM + ih*64 + il];
    }
    __syncthreads();
    for (int idx = tid; idx < 64*64; idx += BDIM) {
      int bb = idx & 63, il = idx >> 6;
      sigT[((size_t)t*IDIM + ih*64 + il)*64 + bb] = tile[il*65 + bb];
    }
    __syncthreads();                                 // tile reads done before Wl fill
  }
  // ---- encoder weights -> LDS (once; rows ju*4+g, stride WS_E) ----
  for (int idx = tid; idx < 16*640; idx += BDIM) {
    int row = idx / 640, k = idx - row*640;
    int g = row & 3, ju = row >> 2;
    int r = d*4*HDIM + g*HDIM + (js*4 + ju);
    Wl[(size_t)row*WS_E + k] = (k < IDIM) ? eWih[(size_t)r*IDIM + k]
                                          : eWhh[(size_t)r*HDIM + (k - IDIM)];
  }
  // hT / xdT live exclusively in L3 (sc1)
  ast(&hT[((size_t)(0*2 + d)*HDIM + j)*64 + b], 0.f);
  ast(&hT[((size_t)(1*2 + d)*HDIM + j)*64 + b], 0.f);
  if (blk < BATCH && tid < VDIM) {
    float tv = tgt[((size_t)blk*LDEC)*VDIM + tid];
    ast(&xdT[tid*64 + blk], tv > 0.f ? tv : 0.f);
  }
  gbar_full(bar + 29*32, bar + 30*32, NBLK, dead);   // fenced: publish sigT (also syncs Wl fill)

  // ---- encoder ----
  float bsum[4];
  #pragma unroll
  for (int g = 0; g < 4; ++g) {
    int r = __builtin_amdgcn_readfirstlane(d*4*HDIM + g*HDIM + j);
    bsum[g] = eBih[r] + eBhh[r];
  }
  float c = 0.f;
  for (int t = 0; t < TSTEP; ++t) {
    const int cur = t & 1, nxt = cur ^ 1;
    const int td = d ? (TSTEP - 1 - t) : t;
    float acc[4] = {0.f, 0.f, 0.f, 0.f};
    cell_step<IDIM, WS_E, false>(acc, sigT + (size_t)td*IDIM*64,
                                 hT + ((size_t)(cur*2 + d)*HDIM)*64, Wl, b, jj, tid, buf);
    float gi = acc[0]+bsum[0], gf = acc[1]+bsum[1], gg = acc[2]+bsum[2], go = acc[3]+bsum[3];
    float si = 1.f/(1.f+expf(-gi)), sf = 1.f/(1.f+expf(-gf)), so = 1.f/(1.f+expf(-go));
    c = sf*c + si*tanhf(gg);
    ast(&hT[((size_t)(nxt*2 + d)*HDIM + j)*64 + b], so*tanhf(c));
    hbar(bar, d ? 18 : 12, (blk >> 5) & 3, 4, 32u, d ? 23 : 17, dead);  // per-dir
  }
  hbar(bar, 1, blk & 7, 8, 32u, 10, dead);           // joint: all enc cells done

  // ---- decoder weights -> LDS (rows ju*4+g, stride WS_D) ----
  for (int idx = tid; idx < 16*544; idx += BDIM) {
    int row = idx / 544, k = idx - row*544;
    int g = row & 3, ju = row >> 2;
    int r = d*4*HDIM + g*HDIM + (js*4 + ju);
    Wl[(size_t)row*WS_D + k] = (k < VDIM) ? dWih[(size_t)r*VDIM + k]
                                          : dWhh[(size_t)r*HDIM + (k - VDIM)];
  }
  #pragma unroll
  for (int g = 0; g < 4; ++g) {
    int r = __builtin_amdgcn_readfirstlane(d*4*HDIM + g*HDIM + j);
    bsum[g] = dBih[r] + dBhh[r];
  }
  __syncthreads();                                   // Wl(dec) visible block-wide

  for (int s = 0; s < LDEC; ++s) {
    const int cur = s & 1, nxt = cur ^ 1;
    float acc[4] = {0.f, 0.f, 0.f, 0.f};
    cell_step<VDIM, WS_D, true>(acc, xdT, hT + ((size_t)(cur*2 + d)*HDIM)*64,
                                Wl, b, jj, tid, buf);
    float gi = acc[0]+bsum[0], gf = acc[1]+bsum[1], gg = acc[2]+bsum[2], go = acc[3]+bsum[3];
    float si = 1.f/(1.f+expf(-gi)), sf = 1.f/(1.f+expf(-gf)), so = 1.f/(1.f+expf(-go));
    c = sf*c + si*tanhf(gg);
    ast(&hT[((size_t)(nxt*2 + d)*HDIM + j)*64 + b], so*tanhf(c));
    hbar(bar, 1, blk & 7, 8, 32u, 10, dead);         // h visible

    if (blk < BATCH) {                               // logits/argmax/log_softmax
      const int bb = blk, v = tid & 31, kc = tid >> 5;
      const float* hx = hT + (size_t)nxt*2*HDIM*64 + bb;   // [d][k][b] d-major = concat(hf,hb)
      float part = 0.f;
      float rr[32];
      for (int w = 0; w < 4; ++w) {                  // windows of 32 in-flight sc1 loads
        #pragma unroll
        for (int i = 0; i < 32; ++i)
          rr[i] = gl1_sc1(hx + (size_t)(kc*128 + w*32 + i)*64);
        wait_vm0();
        #pragma unroll
        for (int i = 0; i < 32; ++i)
          part += Wout[(size_t)v*(2*HDIM) + kc*128 + w*32 + i] * rr[i];
      }
      red[tid] = part;
      __syncthreads();
      if (tid < VDIM) {
        float lg = red[tid];
        #pragma unroll
        for (int q = 1; q < 8; ++q) lg += red[tid + q*32];
        lg += bOut[tid];
        float m = lg; int mi = tid;                  // argmax, first-index tie rule
        #pragma unroll
        for (int off = 16; off >= 1; off >>= 1) {
          float om = __shfl_xor(m, off, 64);
          int omi  = __shfl_xor(mi, off, 64);
          if (om > m || (om == m && omi < mi)) { m = om; mi = omi; }
        }
        float ex = expf(lg - m), ssum = ex;
        #pragma unroll
        for (int off = 16; off >= 1; off >>= 1) ssum += __shfl_xor(ssum, off, 64);
        out[((size_t)bb*LDEC + s)*VDIM + tid] = lg - m - logf(ssum);
        ast(&xdT[tid*64 + bb], (tid == mi) ? 1.f : 0.f);
      }
    }
    hbar(bar, 1, blk & 7, 8, 32u, 10, dead);         // one-hot visible
  }
}

extern "C" void kernel_launch(void* const* d_in, const int* in_sizes, int n_in,
                              void* d_out, int out_size, void* d_ws, size_t ws_size,
                              hipStream_t stream) {
  if (ws_size < WS_NEED) return;
  char* base = (char*)d_ws;
  hipLaunchKernelGGL(encdec, dim3(NBLK), dim3(BDIM), 0, stream,
    (const float*)d_in[0],  (const float*)d_in[1],
    (const float*)d_in[2],  (const float*)d_in[3],
    (const float*)d_in[4],  (const float*)d_in[5],
    (const float*)d_in[6],  (const float*)d_in[7],
    (const float*)d_in[8],  (const float*)d_in[9],
    (const float*)d_in[10], (const float*)d_in[11],
    (float*)d_out,
    (unsigned*)(base + OFF_BAR), (float*)(base + OFF_SIGT),
    (float*)(base + OFF_HT),     (float*)(base + OFF_XD));
}